// Round 7
// baseline (261.714 us; speedup 1.0000x reference)
//
#include <hip/hip_runtime.h>
#include <stdint.h>
#include <stddef.h>

// ---------------------------------------------------------------------------
// MultiHeadAttention: B=8 S=1024 D=1024 H=16 HD=64  (fp32 in/out, bf16 MFMA)
// R7: QKV GEMM -> 256x256 8-wave 4-phase/K-tile schedule (m201-class):
// raw s_barrier (no compiler vmcnt drain), manual vmcnt(0) once per K-tile
// after MFMA, setprio around MFMA cluster, need-aligned async staging.
// ---------------------------------------------------------------------------

typedef short bf16x8 __attribute__((ext_vector_type(8)));   // 8 bf16 = 4 VGPR
typedef float f32x4  __attribute__((ext_vector_type(4)));
typedef unsigned short u16x8 __attribute__((ext_vector_type(8)));
typedef unsigned short u16x4 __attribute__((ext_vector_type(4)));

#define MFMA16 __builtin_amdgcn_mfma_f32_16x16x32_bf16

typedef const void __attribute__((address_space(1)))* gas1_t;
typedef void __attribute__((address_space(3)))* las3_t;

static __device__ __forceinline__ void gload16(const void* g, void* l) {
  // async global->LDS, 16B/lane, dest = wave-uniform base + lane*16
  __builtin_amdgcn_global_load_lds((gas1_t)g, (las3_t)l, 16, 0, 0);
}

static __device__ __forceinline__ unsigned short f2bf(float f) {
  union { float f; unsigned int u; } v; v.f = f;
  unsigned int r = v.u + 0x7fffu + ((v.u >> 16) & 1u);   // RNE
  return (unsigned short)(r >> 16);
}

// ---------------- cast inputs to bf16 ----------------
__global__ __launch_bounds__(256) void cast_all(
    const float* __restrict__ x, const float* __restrict__ Wq,
    const float* __restrict__ Wk, const float* __restrict__ Wv,
    const float* __restrict__ Wo,
    unsigned short* __restrict__ xb, unsigned short* __restrict__ wqkv,
    unsigned short* __restrict__ wob) {
  int base = (blockIdx.x * 256 + threadIdx.x) * 4;
  const float* s; unsigned short* d;
  if (base < 8388608) { s = x + base; d = xb + base; }
  else if (base < 11534336) {
    int o = base - 8388608; int wi = o >> 20;
    const float* w = (wi == 0) ? Wq : (wi == 1) ? Wk : Wv;
    s = w + (o & 1048575); d = wqkv + o;
  } else {
    int o = base - 11534336; s = Wo + o; d = wob + o;
  }
  float4 f = *(const float4*)s;
  u16x4 r; r[0] = f2bf(f.x); r[1] = f2bf(f.y); r[2] = f2bf(f.z); r[3] = f2bf(f.w);
  *(u16x4*)d = r;
}

// ---------------- 256x256 QKV GEMM, 8 waves, 4-phase/K-tile ----------------
// C = A * B^T; A = xb [8192,1024], Bm = wqkv [3072,1024] (torch [out,in]).
// Wave (wr,wc) = (w>>2, w&3) owns output rows [wr*128,+128) x cols [wc*64,+64).
// Phase (qm,kk): 16 MFMA = 4 mrows (qm quadrant) x 4 ncols at K-slice kk.
// Staging: need-aligned (wave stages only its own A-half / B-half), 2 async
// loads per phase; single vmcnt(0) per K-tile placed AFTER last MFMA cluster.
// Raw s_barrier throughout (no compiler-inserted vmcnt(0) drain).
__global__ __launch_bounds__(512, 2) void gemm256_qkv(
    const unsigned short* __restrict__ Ag, const unsigned short* __restrict__ Bg,
    unsigned short* __restrict__ Qo, unsigned short* __restrict__ Ko,
    unsigned short* __restrict__ Vo,
    const float* __restrict__ bq, const float* __restrict__ bk,
    const float* __restrict__ bv) {
  __shared__ __align__(16) char sm[131072];       // 2 x (A 32K + B 32K)
  const int tid = threadIdx.x, lane = tid & 63, w = tid >> 6;
  const int wr = w >> 2, wc = w & 3;              // 2 x 4 wave grid
  const int l15 = lane & 15, g = lane >> 4;
  const int bcol = blockIdx.x * 256, brow = blockIdx.y * 256;

  // stage 2 of the 8 per-tile async loads (phase p): p<2 -> A-half(wr), else
  // B-half(wc>>1). Each load: 64 lanes x 16B = 8 rows x 64 cols, linear LDS
  // dest (wave-uniform base), pre-swizzled global source chunk (rule #21).
  auto stage2 = [&](int kt, int buf, int p) {
#pragma unroll
    for (int jj = 0; jj < 2; ++jj) {
      int rowBase, region;
      const unsigned short* src;
      if (p < 2) {
        int j = p * 2 + jj;
        rowBase = wr * 128 + wc * 32 + j * 8;
        region = 0; src = Ag + (size_t)(brow + rowBase) * 1024;
      } else {
        int j = (p - 2) * 2 + jj;
        rowBase = (wc >> 1) * 128 + (wr * 2 + (wc & 1)) * 32 + j * 8;
        region = 32768; src = Bg + (size_t)(bcol + rowBase) * 1024;
      }
      int rlo = lane >> 3;                        // row within 8-row slab
      int cl = (lane & 7) ^ ((rowBase + rlo) & 7);
      gload16(src + (size_t)rlo * 1024 + kt * 64 + cl * 8,
              sm + buf * 65536 + region + rowBase * 128);
    }
  };

  // prologue: stage tile 0 fully, drain, join
#pragma unroll
  for (int p = 0; p < 4; ++p) stage2(0, 0, p);
  asm volatile("s_waitcnt vmcnt(0)" ::: "memory");
  __builtin_amdgcn_s_barrier();

  f32x4 acc[8][4] = {};
  bf16x8 bfr[4];
  for (int t = 0; t < 16; ++t) {
    const int cur = t & 1;
    const char* As = sm + cur * 65536;
    const char* Bs = As + 32768;
#pragma unroll
    for (int ph = 0; ph < 4; ++ph) {
      const int qm = ph & 1, kk = ph >> 1;        // (0,0),(1,0),(0,1),(1,1)
      if (qm == 0) {                              // b-frags once per kk
#pragma unroll
        for (int nc = 0; nc < 4; ++nc) {
          int row = wc * 64 + nc * 16 + l15;
          int off = (row * 128 + kk * 64 + g * 16) ^ ((row & 7) << 4);
          bfr[nc] = *(const bf16x8*)(Bs + off);
        }
      }
      bf16x8 af[4];
#pragma unroll
      for (int mr = 0; mr < 4; ++mr) {
        int row = wr * 128 + qm * 64 + mr * 16 + l15;
        int off = (row * 128 + kk * 64 + g * 16) ^ ((row & 7) << 4);
        af[mr] = *(const bf16x8*)(As + off);
      }
      if (t < 15) stage2(t + 1, cur ^ 1, ph);     // async, stays in flight
      __builtin_amdgcn_s_barrier();               // raw: no vmcnt drain
      __builtin_amdgcn_s_setprio(1);
#pragma unroll
      for (int mr = 0; mr < 4; ++mr)
#pragma unroll
        for (int nc = 0; nc < 4; ++nc)
          acc[qm * 4 + mr][nc] = MFMA16(af[mr], bfr[nc], acc[qm * 4 + mr][nc], 0, 0, 0);
      __builtin_amdgcn_s_setprio(0);
      if (ph == 3)                                // once per K-tile, after MFMA
        asm volatile("s_waitcnt vmcnt(0)" ::: "memory");
      __builtin_amdgcn_s_barrier();
    }
  }

  // epilogue: C/D frag map col=lane&15, row=g*4+r (m89-verified).
  // n-span per (wc,nc) is 16 cols, 16-aligned -> t/h wave-uniform per group.
  const int bb_ = brow >> 10;                     // 256-tile within one batch
#pragma unroll
  for (int nc = 0; nc < 4; ++nc) {
    int n = bcol + wc * 64 + nc * 16 + l15;
    int tt = n >> 10, nh = n & 1023;
    int h = nh >> 6, hd = nh & 63;
    const float* bias = (tt == 0) ? bq : (tt == 1) ? bk : bv;
    float bbv = bias[nh];
    if (tt == 2) {
      // V^T: [(b*16+h)*64+hd][1024 s]; 4 consecutive s -> one 8B store
      size_t vtb = ((size_t)(bb_ * 16 + h) * 64 + hd) * 1024;
#pragma unroll
      for (int qm = 0; qm < 2; ++qm)
#pragma unroll
        for (int mr = 0; mr < 4; ++mr) {
          int m0 = brow + wr * 128 + qm * 64 + mr * 16 + g * 4;
          int srow0 = m0 & 1023;
          u16x4 vv;
#pragma unroll
          for (int r = 0; r < 4; ++r) vv[r] = f2bf(acc[qm * 4 + mr][nc][r] + bbv);
          *(u16x4*)(Vo + vtb + srow0) = vv;
        }
    } else {
      float scale = (tt == 0) ? 0.125f : 1.0f;    // fold 1/sqrt(HD) into Q
      unsigned short* dst = (tt == 0) ? Qo : Ko;
      size_t basei = ((size_t)(bb_ * 16 + h) * 1024) * 64 + hd;
#pragma unroll
      for (int qm = 0; qm < 2; ++qm)
#pragma unroll
        for (int mr = 0; mr < 4; ++mr)
#pragma unroll
          for (int r = 0; r < 4; ++r) {
            int m = brow + wr * 128 + qm * 64 + mr * 16 + g * 4 + r;
            dst[basei + (size_t)(m & 1023) * 64] = f2bf((acc[qm * 4 + mr][nc][r] + bbv) * scale);
          }
    }
  }
}

// ---------------- 128x128 bf16 GEMM (out-proj), dbuf pipeline ----------------
__global__ __launch_bounds__(256) void gemm128_out(
    const unsigned short* __restrict__ A, const unsigned short* __restrict__ Bm,
    float* __restrict__ Cf, const float* __restrict__ bO) {
  __shared__ __align__(16) char sm[65536];        // 2 x (As 16K + Bs 16K)
  const int tid = threadIdx.x, lane = tid & 63, w = tid >> 6;
  const int wr = w >> 1, wc = w & 1;
  const int bcol = (blockIdx.x & 7) * 128, brow = (blockIdx.x >> 3) * 128;
  const int l15 = lane & 15, g = lane >> 4;

  auto stage = [&](int ks, int buf) {
    char* Ad = sm + buf * 32768;
    char* Bd = Ad + 16384;
#pragma unroll
    for (int jj = 0; jj < 4; ++jj) {
      int p = (w * 4 + jj) * 1024 + lane * 16;
      int row = p >> 7;
      int cl = (lane & 7) ^ (row & 7);
      gload16(A + (size_t)(brow + row) * 1024 + ks * 64 + cl * 8,
              Ad + (w * 4 + jj) * 1024);
      gload16(Bm + (size_t)(bcol + row) * 1024 + ks * 64 + cl * 8,
              Bd + (w * 4 + jj) * 1024);
    }
  };

  stage(0, 0);
  asm volatile("s_waitcnt vmcnt(0)" ::: "memory");
  __syncthreads();

  f32x4 acc[4][4] = {};
  for (int ks = 0; ks < 16; ++ks) {
    const int cur = ks & 1;
    if (ks < 15) stage(ks + 1, cur ^ 1);
    const char* As = sm + cur * 32768;
    const char* Bs = As + 16384;
#pragma unroll
    for (int kk = 0; kk < 2; ++kk) {
      bf16x8 af[4], bfr[4];
#pragma unroll
      for (int mi = 0; mi < 4; ++mi) {
        int row = wr * 64 + mi * 16 + l15;
        int off = (row * 128 + kk * 64 + g * 16) ^ ((row & 7) << 4);
        af[mi] = *(const bf16x8*)(As + off);
      }
#pragma unroll
      for (int ni = 0; ni < 4; ++ni) {
        int row = wc * 64 + ni * 16 + l15;
        int off = (row * 128 + kk * 64 + g * 16) ^ ((row & 7) << 4);
        bfr[ni] = *(const bf16x8*)(Bs + off);
      }
#pragma unroll
      for (int mi = 0; mi < 4; ++mi)
#pragma unroll
        for (int ni = 0; ni < 4; ++ni)
          acc[mi][ni] = MFMA16(af[mi], bfr[ni], acc[mi][ni], 0, 0, 0);
    }
    asm volatile("s_waitcnt vmcnt(0)" ::: "memory");
    __syncthreads();
  }
#pragma unroll
  for (int ni = 0; ni < 4; ++ni) {
    int n = bcol + wc * 64 + ni * 16 + l15;
    float bb = bO[n];
#pragma unroll
    for (int mi = 0; mi < 4; ++mi)
#pragma unroll
      for (int r = 0; r < 4; ++r) {
        int m = brow + wr * 64 + mi * 16 + g * 4 + r;
        Cf[(size_t)m * 1024 + n] = acc[mi][ni][r] + bb;
      }
  }
}

// ---------------- fused flash attention (O^T orientation) ----------------
// 1-D grid 1024: id = qt*128 + bh. 256 thr = 4 waves, 32 q/wave.
// S^T = mfma(K, Q); O^T = mfma(V^T, P) -> per-lane softmax state, no shuffles.
__global__ __launch_bounds__(256, 3) void attn_fused(
    const unsigned short* __restrict__ Qb, const unsigned short* __restrict__ Kb,
    const unsigned short* __restrict__ VtG, unsigned short* __restrict__ Cc) {
  __shared__ __align__(16) char sm[49152];
  char* Ks = sm;                    // 2 x [64 s][64 d] bf16, XOR-swizzled (16K)
  char* Vt = sm + 16384;            // 2 x [64 d][64 s] bf16, XOR-swizzled (16K)
  const int tid = threadIdx.x, lane = tid & 63, w = tid >> 6;
  char* Ps = sm + 32768 + w * 4096; // per-wave [32 q][64 s] bf16, XOR-swizzled
  const int l15 = lane & 15, g = lane >> 4;
  const int id = blockIdx.x;
  const int qt = id >> 7, bh = id & 127;          // head-locality decode
  const size_t hb = (size_t)bh * (1024 * 64);

  bf16x8 qreg[2][2];                               // [kk][ni]
#pragma unroll
  for (int kk = 0; kk < 2; ++kk)
#pragma unroll
    for (int ni = 0; ni < 2; ++ni) {
      int q = qt * 128 + w * 32 + ni * 16 + l15;
      qreg[kk][ni] = *(const bf16x8*)(Qb + hb + (size_t)q * 64 + kk * 32 + g * 8);
    }

  auto stage = [&](int c, int buf) {
#pragma unroll
    for (int j = 0; j < 2; ++j) {
      int p = (w * 2 + j) * 1024 + lane * 16;
      int row = p >> 7;
      int cl = (lane & 7) ^ (row & 7);
      gload16(Kb + hb + (size_t)(c * 64 + row) * 64 + cl * 8,
              Ks + buf * 8192 + (w * 2 + j) * 1024);
      gload16(VtG + hb + (size_t)row * 1024 + c * 64 + cl * 8,
              Vt + buf * 8192 + (w * 2 + j) * 1024);
    }
  };

  stage(0, 0);
  asm volatile("s_waitcnt vmcnt(0)" ::: "memory");
  __syncthreads();

  f32x4 acc[4][2] = {};                            // O^T [nd][ni]
  float m_run[2] = {-1e30f, -1e30f};
  float l_run[2] = {0.f, 0.f};

  for (int c = 0; c < 16; ++c) {
    const int cur = c & 1;
    if (c < 15) stage(c + 1, cur ^ 1);
    const char* Kc = Ks + cur * 8192;
    const char* Vc = Vt + cur * 8192;

    f32x4 st[4][2] = {};
#pragma unroll
    for (int kk = 0; kk < 2; ++kk) {
      bf16x8 ka[4];
#pragma unroll
      for (int mi = 0; mi < 4; ++mi) {
        int row = mi * 16 + l15;
        int off = (row * 128 + kk * 64 + g * 16) ^ ((row & 7) << 4);
        ka[mi] = *(const bf16x8*)(Kc + off);
      }
#pragma unroll
      for (int mi = 0; mi < 4; ++mi)
#pragma unroll
        for (int ni = 0; ni < 2; ++ni)
          st[mi][ni] = MFMA16(ka[mi], qreg[kk][ni], st[mi][ni], 0, 0, 0);
    }

    float corr_s[2];
#pragma unroll
    for (int ni = 0; ni < 2; ++ni) {
      float mx = -1e30f;
#pragma unroll
      for (int mi = 0; mi < 4; ++mi)
#pragma unroll
        for (int r = 0; r < 4; ++r) mx = fmaxf(mx, st[mi][ni][r]);
      mx = fmaxf(mx, __shfl_xor(mx, 16));
      mx = fmaxf(mx, __shfl_xor(mx, 32));
      float mn = fmaxf(m_run[ni], mx);
      float corr = __expf(m_run[ni] - mn);
      float sum = 0.f;
      const int q = ni * 16 + l15;
      const int rbase = q * 128, sw = (q & 7) << 4;
#pragma unroll
      for (int mi = 0; mi < 4; ++mi) {
        u16x4 pk;
#pragma unroll
        for (int r = 0; r < 4; ++r) {
          float e = __expf(st[mi][ni][r] - mn);
          sum += e;
          pk[r] = f2bf(e);
        }
        *(u16x4*)(Ps + ((rbase + (mi * 16 + g * 4) * 2) ^ sw)) = pk;
      }
      sum += __shfl_xor(sum, 16);
      sum += __shfl_xor(sum, 32);
      l_run[ni] = l_run[ni] * corr + sum;
      m_run[ni] = mn;
      corr_s[ni] = corr;
    }

#pragma unroll
    for (int nd = 0; nd < 4; ++nd)
#pragma unroll
      for (int ni = 0; ni < 2; ++ni)
#pragma unroll
        for (int r = 0; r < 4; ++r)
          acc[nd][ni][r] *= corr_s[ni];

#pragma unroll
    for (int kk = 0; kk < 2; ++kk) {
      bf16x8 vf[4], pa[2];
#pragma unroll
      for (int nd = 0; nd < 4; ++nd) {
        int row = nd * 16 + l15;
        int off = (row * 128 + kk * 64 + g * 16) ^ ((row & 7) << 4);
        vf[nd] = *(const bf16x8*)(Vc + off);
      }
#pragma unroll
      for (int ni = 0; ni < 2; ++ni) {
        int q = ni * 16 + l15;
        int off = (q * 128 + kk * 64 + g * 16) ^ ((q & 7) << 4);
        pa[ni] = *(const bf16x8*)(Ps + off);
      }
#pragma unroll
      for (int nd = 0; nd < 4; ++nd)
#pragma unroll
        for (int ni = 0; ni < 2; ++ni)
          acc[nd][ni] = MFMA16(vf[nd], pa[ni], acc[nd][ni], 0, 0, 0);
    }

    asm volatile("s_waitcnt vmcnt(0)" ::: "memory");
    __syncthreads();
  }

  const int b = bh >> 4, h = bh & 15;
  float invl[2] = {1.f / l_run[0], 1.f / l_run[1]};
#pragma unroll
  for (int ni = 0; ni < 2; ++ni) {
    int q = qt * 128 + w * 32 + ni * 16 + l15;
    size_t rowb = (size_t)(b * 1024 + q) * 1024 + h * 64;
#pragma unroll
    for (int nd = 0; nd < 4; ++nd) {
      u16x4 o;
#pragma unroll
      for (int r = 0; r < 4; ++r) o[r] = f2bf(acc[nd][ni][r] * invl[ni]);
      *(u16x4*)(Cc + rowb + nd * 16 + g * 4) = o;
    }
  }
}

// ---------------- launch ----------------
extern "C" void kernel_launch(void* const* d_in, const int* in_sizes, int n_in,
                              void* d_out, int out_size, void* d_ws, size_t ws_size,
                              hipStream_t stream) {
  const float* x  = (const float*)d_in[0];
  const float* Wq = (const float*)d_in[1];
  const float* Wk = (const float*)d_in[2];
  const float* Wv = (const float*)d_in[3];
  const float* bq = (const float*)d_in[4];
  const float* bk = (const float*)d_in[5];
  const float* bv = (const float*)d_in[6];
  const float* Wo = (const float*)d_in[7];
  const float* bo = (const float*)d_in[8];

  char* ws = (char*)d_ws;
  unsigned short* xb   = (unsigned short*)(ws);               // 16 MB (dead after QKV gemm)
  unsigned short* wqkv = (unsigned short*)(ws + 16777216);    //  6 MB [3][1024][1024]
  unsigned short* wob  = (unsigned short*)(ws + 23068672);    //  2 MB
  unsigned short* Qb   = (unsigned short*)(ws + 25165824);    // 16 MB [B,H,S,64]
  unsigned short* Kb   = (unsigned short*)(ws + 41943040);    // 16 MB [B,H,S,64]
  unsigned short* VtG  = (unsigned short*)(ws + 58720256);    // 16 MB [B*H,64,1024] (V^T)
  unsigned short* Cc   = xb;   // alias: xb dead after QKV gemm; peak ws = 75.5 MB

  cast_all<<<dim3(12288), dim3(256), 0, stream>>>(x, Wq, Wk, Wv, Wo, xb, wqkv, wob);
  gemm256_qkv<<<dim3(12, 32), dim3(512), 0, stream>>>(
      xb, wqkv, Qb, Kb, VtG, bq, bk, bv);
  attn_fused<<<dim3(1024), dim3(256), 0, stream>>>(Qb, Kb, VtG, Cc);
  gemm128_out<<<dim3(512), dim3(256), 0, stream>>>(Cc, wob, (float*)d_out, bo);
}